// Round 3
// baseline (965.368 us; speedup 1.0000x reference)
//
#include <hip/hip_runtime.h>
#include <stdint.h>

#define NE 8
#define NI 2816
#define NH 1024
#define NT 8192
#define NPAIR (NT * 2)

typedef __bf16 bf16x8 __attribute__((ext_vector_type(8)));
typedef float f32x4 __attribute__((ext_vector_type(4)));

__device__ __forceinline__ uint16_t f2bf(float f) {
    union { float f; uint32_t u; } v;
    v.f = f;
    return (uint16_t)((v.u + 0x7FFFu + ((v.u >> 16) & 1u)) >> 16);
}

__device__ __forceinline__ float bflo(uint32_t u) {
    union { uint32_t x; float f; } v; v.x = u << 16; return v.f;
}
__device__ __forceinline__ float bfhi(uint32_t u) {
    union { uint32_t x; float f; } v; v.x = u & 0xffff0000u; return v.f;
}

// async global->LDS, 16B per lane. LDS dest must be lane-contiguous (wave-uniform
// base + lane*16). Generic->AS3 via 32-bit truncation (LDS aperture is 4GB-aligned).
__device__ __forceinline__ void gld16(const void* g, void* l) {
    __builtin_amdgcn_global_load_lds(
        (__attribute__((address_space(1))) void*)(uintptr_t)g,
        (__attribute__((address_space(3))) void*)(uint32_t)(uintptr_t)l,
        16, 0, 0);
}

// LDS bank-group swizzle: LDS[row][g] holds global granule g ^ perm(row).
// perm(r+16) == perm(r), so fragment offsets of it*16 rows keep one base ptr.
__device__ __forceinline__ int granperm(int r) {
    return (r & 3) ^ ((r >> 2) & 3);
}

// ---------------- fp32 -> bf16 weight conversion (all 3 weights, one launch) ----
__global__ __launch_bounds__(256) void k_cvt3(const float* __restrict__ W1,
                                              const float* __restrict__ W3,
                                              const float* __restrict__ W2,
                                              uint16_t* __restrict__ W1b,
                                              uint16_t* __restrict__ W3b,
                                              uint16_t* __restrict__ W2b) {
    int i = blockIdx.x * 256 + threadIdx.x;  // [0, WELEMS/8)
    const float* s = blockIdx.y == 0 ? W1 : (blockIdx.y == 1 ? W3 : W2);
    uint16_t* d = blockIdx.y == 0 ? W1b : (blockIdx.y == 1 ? W3b : W2b);
    float4 a = ((const float4*)s)[(size_t)i * 2];
    float4 b = ((const float4*)s)[(size_t)i * 2 + 1];
    uint4 o;
    o.x = (uint32_t)f2bf(a.x) | ((uint32_t)f2bf(a.y) << 16);
    o.y = (uint32_t)f2bf(a.z) | ((uint32_t)f2bf(a.w) << 16);
    o.z = (uint32_t)f2bf(b.x) | ((uint32_t)f2bf(b.y) << 16);
    o.w = (uint32_t)f2bf(b.z) | ((uint32_t)f2bf(b.w) << 16);
    ((uint4*)d)[i] = o;
}

// ---------------- router: top-2 of softmax, renormalized ----------------
__global__ __launch_bounds__(256) void k_router(const float* __restrict__ logits,
                                                int* __restrict__ tok_e,
                                                float2* __restrict__ tok_w,
                                                int* __restrict__ counts) {
    int t = blockIdx.x * 256 + threadIdx.x;
    if (t >= NT) return;
    float4 a = ((const float4*)logits)[(size_t)t * 2];
    float4 b = ((const float4*)logits)[(size_t)t * 2 + 1];
    float l[8] = {a.x, a.y, a.z, a.w, b.x, b.y, b.z, b.w};
    int i0 = 0; float l0 = l[0];
#pragma unroll
    for (int e = 1; e < 8; e++) if (l[e] > l0) { l0 = l[e]; i0 = e; }
    int i1 = -1; float l1 = -3.4e38f;
#pragma unroll
    for (int e = 0; e < 8; e++) if (e != i0 && l[e] > l1) { l1 = l[e]; i1 = e; }
    float w0 = 1.f / (1.f + __expf(l1 - l0));
    float w1 = 1.f - w0;
    tok_e[t] = i0 | (i1 << 8);
    tok_w[t] = make_float2(w0, w1);
    atomicAdd(&counts[i0], 1);
    atomicAdd(&counts[i1], 1);
}

__global__ void k_scan(const int* __restrict__ counts, int* __restrict__ offsets,
                       int* __restrict__ cursor) {
    if (threadIdx.x == 0) {
        int o = 0;
        for (int e = 0; e < NE; e++) { offsets[e] = o; cursor[e] = o; o += counts[e]; }
    }
}

// ---------------- gather routed x rows into per-expert bf16 panels ----------------
__global__ __launch_bounds__(128) void k_gather(const float* __restrict__ x,
                                                const int* __restrict__ tok_e,
                                                const float2* __restrict__ tok_w,
                                                int* __restrict__ cursor,
                                                uint16_t* __restrict__ Xg,
                                                int2* __restrict__ tok_slots,
                                                float* __restrict__ slot_w) {
    int t = blockIdx.x;
    __shared__ int ss[2];
    if (threadIdx.x == 0) {
        int ee = tok_e[t];
        float2 w = tok_w[t];
        int s0 = atomicAdd(&cursor[ee & 0xff], 1);
        int s1 = atomicAdd(&cursor[(ee >> 8) & 0xff], 1);
        ss[0] = s0; ss[1] = s1;
        tok_slots[t] = make_int2(s0, s1);
        slot_w[s0] = w.x;
        slot_w[s1] = w.y;
    }
    __syncthreads();
    int s0 = ss[0], s1 = ss[1];
    int i = threadIdx.x;  // 8 floats each
    const float4* xr = (const float4*)(x + (size_t)t * NH);
    float4 a = xr[i * 2];
    float4 b = xr[i * 2 + 1];
    uint4 o;
    o.x = (uint32_t)f2bf(a.x) | ((uint32_t)f2bf(a.y) << 16);
    o.y = (uint32_t)f2bf(a.z) | ((uint32_t)f2bf(a.w) << 16);
    o.z = (uint32_t)f2bf(b.x) | ((uint32_t)f2bf(b.y) << 16);
    o.w = (uint32_t)f2bf(b.z) | ((uint32_t)f2bf(b.w) << 16);
    ((uint4*)(Xg + (size_t)s0 * NH))[i] = o;
    ((uint4*)(Xg + (size_t)s1 * NH))[i] = o;
}

// ---------------- G1: Hbuf = silu(X@W1^T) * (X@W3^T), per expert ----------------
// 512 threads = 8 waves; each wave owns a 64x32 quadrant (wrow=wv&1, wcol=wv>>1).
// acc = 64 f32/lane (vs 128 in the 4-wave version) -> 4 waves/SIMD occupancy.
__global__ __launch_bounds__(512, 4) void k_gemm1(const uint16_t* __restrict__ Xg,
                                                  const uint16_t* __restrict__ W1b,
                                                  const uint16_t* __restrict__ W3b,
                                                  uint16_t* __restrict__ Hbuf,
                                                  const int* __restrict__ counts,
                                                  const int* __restrict__ offsets) {
    int e = blockIdx.z;
    int n_e = counts[e];
    int mtile = blockIdx.y;
    if (mtile * 128 >= n_e) return;
    int ntile = blockIdx.x;
    int off = offsets[e];

    __shared__ __align__(16) uint16_t As[128 * 32];
    __shared__ __align__(16) uint16_t B1s[128 * 32];
    __shared__ __align__(16) uint16_t B3s[128 * 32];

    int tid = threadIdx.x;
    int r = tid >> 2, c = tid & 3;
    int wv = tid >> 6, lane = tid & 63;
    int wrow = wv & 1, wcol = wv >> 1;       // 2 x 4 wave grid, 64x32 each
    int m_in = lane & 15, q = lane >> 4;

    int pg = c ^ granperm(r);                // swizzled global granule to fetch

    int rowA = min(off + mtile * 128 + r, NPAIR - 1);
    const uint16_t* a0 = Xg + (size_t)rowA * NH + pg * 8;
    const uint16_t* b1r = W1b + ((size_t)e * NI + ntile * 128 + r) * NH + pg * 8;
    const uint16_t* b3r = W3b + ((size_t)e * NI + ntile * 128 + r) * NH + pg * 8;

    uint16_t* lA = &As[tid * 8];
    uint16_t* lB1 = &B1s[tid * 8];
    uint16_t* lB3 = &B3s[tid * 8];

    int arow = wrow * 64 + m_in;
    int aq = q ^ granperm(arow);
    const uint16_t* pa = &As[arow * 32 + aq * 8];
    int brow = wcol * 32 + m_in;
    int bq = q ^ granperm(brow);
    const uint16_t* pb1 = &B1s[brow * 32 + bq * 8];
    const uint16_t* pb3 = &B3s[brow * 32 + bq * 8];

    f32x4 acc1[4][2] = {};
    f32x4 acc3[4][2] = {};

    for (int k0 = 0; k0 < NH; k0 += 32) {
        gld16(a0 + k0, lA);
        gld16(b1r + k0, lB1);
        gld16(b3r + k0, lB3);
        __syncthreads();

        bf16x8 af[4], b1f[2], b3f[2];
#pragma unroll
        for (int it = 0; it < 4; it++) af[it] = *(const bf16x8*)(pa + it * 512);
#pragma unroll
        for (int jt = 0; jt < 2; jt++) {
            b1f[jt] = *(const bf16x8*)(pb1 + jt * 512);
            b3f[jt] = *(const bf16x8*)(pb3 + jt * 512);
        }
#pragma unroll
        for (int it = 0; it < 4; it++)
#pragma unroll
            for (int jt = 0; jt < 2; jt++) {
                acc1[it][jt] = __builtin_amdgcn_mfma_f32_16x16x32_bf16(af[it], b1f[jt], acc1[it][jt], 0, 0, 0);
                acc3[it][jt] = __builtin_amdgcn_mfma_f32_16x16x32_bf16(af[it], b3f[jt], acc3[it][jt], 0, 0, 0);
            }
        __syncthreads();
    }

    int sBase = off + mtile * 128;
#pragma unroll
    for (int it = 0; it < 4; it++) {
#pragma unroll
        for (int reg = 0; reg < 4; reg++) {
            int lm = wrow * 64 + it * 16 + q * 4 + reg;
            if (mtile * 128 + lm < n_e) {
                uint16_t* orow = Hbuf + (size_t)(sBase + lm) * NI + ntile * 128 + wcol * 32 + m_in;
#pragma unroll
                for (int jt = 0; jt < 2; jt++) {
                    float c1 = acc1[it][jt][reg];
                    float c3 = acc3[it][jt][reg];
                    float hv = (c1 / (1.f + __expf(-c1))) * c3;  // silu(c1)*c3
                    orow[jt * 16] = f2bf(hv);
                }
            }
        }
    }
}

// ---------------- G2: Ybuf[slot] = H @ W2^T (unweighted, plain bf16 stores) ------
__global__ __launch_bounds__(512, 6) void k_gemm2(const uint16_t* __restrict__ Hbuf,
                                                  const uint16_t* __restrict__ W2b,
                                                  uint16_t* __restrict__ Ybuf,
                                                  const int* __restrict__ counts,
                                                  const int* __restrict__ offsets) {
    int e = blockIdx.z;
    int n_e = counts[e];
    int mtile = blockIdx.y;
    if (mtile * 128 >= n_e) return;
    int ntile = blockIdx.x;  // 0..7
    int off = offsets[e];

    __shared__ __align__(16) uint16_t As[128 * 32];
    __shared__ __align__(16) uint16_t Bs[128 * 32];

    int tid = threadIdx.x;
    int r = tid >> 2, c = tid & 3;
    int wv = tid >> 6, lane = tid & 63;
    int wrow = wv & 1, wcol = wv >> 1;
    int m_in = lane & 15, q = lane >> 4;

    int pg = c ^ granperm(r);

    int rowA = min(off + mtile * 128 + r, NPAIR - 1);
    const uint16_t* a0 = Hbuf + (size_t)rowA * NI + pg * 8;
    const uint16_t* br = W2b + ((size_t)e * NH + ntile * 128 + r) * NI + pg * 8;

    uint16_t* lA = &As[tid * 8];
    uint16_t* lB = &Bs[tid * 8];

    int arow = wrow * 64 + m_in;
    int aq = q ^ granperm(arow);
    const uint16_t* pa = &As[arow * 32 + aq * 8];
    int brow = wcol * 32 + m_in;
    int bq = q ^ granperm(brow);
    const uint16_t* pb = &Bs[brow * 32 + bq * 8];

    f32x4 acc[4][2] = {};

    for (int k0 = 0; k0 < NI; k0 += 32) {
        gld16(a0 + k0, lA);
        gld16(br + k0, lB);
        __syncthreads();

        bf16x8 af[4], bf[2];
#pragma unroll
        for (int it = 0; it < 4; it++) af[it] = *(const bf16x8*)(pa + it * 512);
#pragma unroll
        for (int jt = 0; jt < 2; jt++) bf[jt] = *(const bf16x8*)(pb + jt * 512);
#pragma unroll
        for (int it = 0; it < 4; it++)
#pragma unroll
            for (int jt = 0; jt < 2; jt++)
                acc[it][jt] = __builtin_amdgcn_mfma_f32_16x16x32_bf16(af[it], bf[jt], acc[it][jt], 0, 0, 0);
        __syncthreads();
    }

    int sBase = off + mtile * 128;
#pragma unroll
    for (int it = 0; it < 4; it++) {
#pragma unroll
        for (int reg = 0; reg < 4; reg++) {
            int lm = wrow * 64 + it * 16 + q * 4 + reg;
            if (mtile * 128 + lm < n_e) {
                uint16_t* orow = Ybuf + (size_t)(sBase + lm) * NH + ntile * 128 + wcol * 32 + m_in;
#pragma unroll
                for (int jt = 0; jt < 2; jt++)
                    orow[jt * 16] = f2bf(acc[it][jt][reg]);
            }
        }
    }
}

// ---------------- combine: out[t] = w0*Y[s0] + w1*Y[s1] (fp32) ----------------
__global__ __launch_bounds__(256) void k_combine(const uint16_t* __restrict__ Y,
                                                 const int2* __restrict__ tok_slots,
                                                 const float* __restrict__ slot_w,
                                                 float* __restrict__ out) {
    int idx = blockIdx.x * 256 + threadIdx.x;  // NT*NH/8 threads
    int t = idx >> 7;
    int g = idx & 127;
    int2 s = tok_slots[t];
    float w0 = slot_w[s.x], w1 = slot_w[s.y];
    uint4 u0 = ((const uint4*)(Y + (size_t)s.x * NH))[g];
    uint4 u1 = ((const uint4*)(Y + (size_t)s.y * NH))[g];
    float4 o0, o1;
    o0.x = w0 * bflo(u0.x) + w1 * bflo(u1.x);
    o0.y = w0 * bfhi(u0.x) + w1 * bfhi(u1.x);
    o0.z = w0 * bflo(u0.y) + w1 * bflo(u1.y);
    o0.w = w0 * bfhi(u0.y) + w1 * bfhi(u1.y);
    o1.x = w0 * bflo(u0.z) + w1 * bflo(u1.z);
    o1.y = w0 * bfhi(u0.z) + w1 * bfhi(u1.z);
    o1.z = w0 * bflo(u0.w) + w1 * bflo(u1.w);
    o1.w = w0 * bfhi(u0.w) + w1 * bfhi(u1.w);
    float4* orow = (float4*)(out + (size_t)t * NH + g * 8);
    orow[0] = o0;
    orow[1] = o1;
}

extern "C" void kernel_launch(void* const* d_in, const int* in_sizes, int n_in,
                              void* d_out, int out_size, void* d_ws, size_t ws_size,
                              hipStream_t stream) {
    const float* x = (const float*)d_in[0];
    const float* logits = (const float*)d_in[1];
    const float* W1 = (const float*)d_in[2];
    const float* W3 = (const float*)d_in[3];
    const float* W2 = (const float*)d_in[4];
    float* out = (float*)d_out;

    char* ws = (char*)d_ws;
    size_t o = 0;
    auto nxt = [&](size_t b) -> void* {
        void* p = ws + o;
        o += (b + 255) & ~(size_t)255;
        return p;
    };
    const size_t WELEMS = (size_t)NE * NI * NH;
    uint16_t* W1b = (uint16_t*)nxt(WELEMS * 2);
    uint16_t* W3b = (uint16_t*)nxt(WELEMS * 2);
    uint16_t* W2b = (uint16_t*)nxt(WELEMS * 2);
    uint16_t* Xg = (uint16_t*)nxt((size_t)NPAIR * NH * 2);  // aliased as Ybuf after gemm1
    uint16_t* Hbuf = (uint16_t*)nxt((size_t)NPAIR * NI * 2);
    float* slot_w = (float*)nxt((size_t)NPAIR * 4);
    int2* tok_slots = (int2*)nxt((size_t)NT * 8);
    int* tok_e = (int*)nxt((size_t)NT * 4);
    float2* tok_w = (float2*)nxt((size_t)NT * 8);
    int* meta = (int*)nxt(128);
    int* counts = meta;
    int* offsets = meta + 8;
    int* cursor = meta + 16;
    uint16_t* Ybuf = Xg;  // Xg dead after gemm1; same size
    (void)ws_size; (void)in_sizes; (void)n_in;

    hipMemsetAsync(meta, 0, 128, stream);

    k_router<<<NT / 256, 256, 0, stream>>>(logits, tok_e, tok_w, counts);
    k_scan<<<1, 64, 0, stream>>>(counts, offsets, cursor);

    k_cvt3<<<dim3((unsigned)(WELEMS / 8 / 256), 3), 256, 0, stream>>>(W1, W3, W2, W1b, W3b, W2b);

    k_gather<<<NT, 128, 0, stream>>>(x, tok_e, tok_w, cursor, Xg, tok_slots, slot_w);

    k_gemm1<<<dim3(NI / 128, NT / 128, NE), 512, 0, stream>>>(Xg, W1b, W3b, Hbuf, counts, offsets);
    k_gemm2<<<dim3(NH / 128, NT / 128, NE), 512, 0, stream>>>(Hbuf, W2b, Ybuf, counts, offsets);
    k_combine<<<NT * NH / 8 / 256, 256, 0, stream>>>(Ybuf, tok_slots, slot_w, out);
}